// Round 4
// baseline (204.322 us; speedup 1.0000x reference)
//
#include <hip/hip_runtime.h>

#define NDIM 4096
#define LDIM 128
#define EDIM 12
#define HDIM 32

typedef float f2 __attribute__((ext_vector_type(2)));

#ifndef __has_builtin
#define __has_builtin(x) 0
#endif

__device__ __forceinline__ float ex2_(float v) {
#if __has_builtin(__builtin_amdgcn_exp2f)
    return __builtin_amdgcn_exp2f(v);
#else
    return exp2f(v);
#endif
}
__device__ __forceinline__ float rcp_(float v) {
#if __has_builtin(__builtin_amdgcn_rcpf)
    return __builtin_amdgcn_rcpf(v);
#else
    return 1.0f / v;
#endif
}
__device__ __forceinline__ float rsq_(float v) {
#if __has_builtin(__builtin_amdgcn_rsqf)
    return __builtin_amdgcn_rsqf(v);
#else
    return rsqrtf(v);
#endif
}
// tanh(v) = 1 - 2/(e^{2v}+1)
__device__ __forceinline__ float tanh_(float v) {
    float t = ex2_(v * 2.8853900817779268f);
    return 1.0f - 2.0f * rcp_(t + 1.0f);
}

__device__ __forceinline__ f2 lo2(float4 v) { f2 r; r.x = v.x; r.y = v.y; return r; }
__device__ __forceinline__ f2 hi2(float4 v) { f2 r; r.x = v.z; r.y = v.w; return r; }
__device__ __forceinline__ f2 pf(f2 a, f2 b, f2 c) { return __builtin_elementwise_fma(a, b, c); }

// unpack bf16 pair (packed uint) -> f2  (2 VALU: lshl, and)
__device__ __forceinline__ f2 up2(unsigned int u) {
    f2 r;
    r.x = __uint_as_float(u << 16);
    r.y = __uint_as_float(u & 0xffff0000u);
    return r;
}
// round-to-nearest-even f32 pair -> packed bf16 uint
__device__ __forceinline__ unsigned int bfpair(float lo, float hi) {
    unsigned int a = __float_as_uint(lo), b = __float_as_uint(hi);
    a = (a + 0x7fffu + ((a >> 16) & 1u)) >> 16;
    b = (b + 0x7fffu + ((b >> 16) & 1u)) >> 16;
    return a | (b << 16);
}

// dot(12-elem weight row (global, uniform -> s_load), f2[6]) via packed fma
__device__ __forceinline__ float dot12p(const float* __restrict__ w, const f2* v) {
    const float4* w4 = reinterpret_cast<const float4*>(w);
    float4 a = w4[0], b = w4[1], c = w4[2];
    f2 s = v[0] * lo2(a);
    s = pf(v[1], hi2(a), s);
    s = pf(v[2], lo2(b), s);
    s = pf(v[3], hi2(b), s);
    s = pf(v[4], lo2(c), s);
    s = pf(v[5], hi2(c), s);
    return s.x + s.y;
}
__device__ __forceinline__ float dot32p(const float* __restrict__ w, const f2* v) {
    const float4* w4 = reinterpret_cast<const float4*>(w);
    f2 s = {0.f, 0.f};
    #pragma unroll
    for (int c = 0; c < 8; ++c) {
        float4 t = w4[c];
        s = pf(v[2*c],   lo2(t), s);
        s = pf(v[2*c+1], hi2(t), s);
    }
    return s.x + s.y;
}

__global__ __launch_bounds__(256, 3)
void encoder_fused(const float* __restrict__ x,
                   const float* __restrict__ inw, const float* __restrict__ inb,
                   const float* __restrict__ ow,  const float* __restrict__ ob,
                   const float* __restrict__ w1,  const float* __restrict__ b1,
                   const float* __restrict__ w2,  const float* __restrict__ b2,
                   const float* __restrict__ w3,  const float* __restrict__ b3,
                   const float* __restrict__ g1,  const float* __restrict__ be1,
                   const float* __restrict__ g2,  const float* __restrict__ be2,
                   float* __restrict__ out)
{
    const int wv = threadIdx.x >> 6;   // wave id 0..3 -> one n per wave
    const int ln = threadIdx.x & 63;   // lane; handles rows ln and ln+64
    const int n  = blockIdx.x * 4 + wv;

    // one 48B record per m: words 0..5 = K bf16 pairs, 6..11 = V bf16 pairs
    __shared__ unsigned int sKV[4][LDIM][12];

    const float SCALE = 0.2886751345948129f;   // 1/sqrt(12)
    const float L2E   = 1.4426950408889634f;

    // ---- load x rows, QKV projection, pack K/V into LDS ----
    f2 xr[2][6];
    f2 qL[2][6];                  // q * SCALE * L2E
    float qq[2];
    float knmx = 0.f;
    #pragma unroll
    for (int rr = 0; rr < 2; ++rr) {
        const int row = ln + 64 * rr;
        const float* xp = x + ((size_t)row * NDIM + n) * EDIM;
        float4 xa = *reinterpret_cast<const float4*>(xp);
        float4 xb = *reinterpret_cast<const float4*>(xp + 4);
        float4 xc = *reinterpret_cast<const float4*>(xp + 8);
        xr[rr][0] = lo2(xa); xr[rr][1] = hi2(xa);
        xr[rr][2] = lo2(xb); xr[rr][3] = hi2(xb);
        xr[rr][4] = lo2(xc); xr[rr][5] = hi2(xc);

        float aq = 0.f;
        #pragma unroll
        for (int f = 0; f < EDIM; f += 2) {
            float a0 = (inb[f]     + dot12p(inw + f * EDIM,       xr[rr])) * SCALE;
            float a1 = (inb[f + 1] + dot12p(inw + (f + 1) * EDIM, xr[rr])) * SCALE;
            aq += a0 * a0 + a1 * a1;
            f2 t; t.x = a0 * L2E; t.y = a1 * L2E;
            qL[rr][f >> 1] = t;
        }
        qq[rr] = aq;

        float kv[EDIM];
        float kn = 0.f;
        #pragma unroll
        for (int f = 0; f < EDIM; ++f) {
            float a = inb[12 + f] + dot12p(inw + (12 + f) * EDIM, xr[rr]);
            kv[f] = a; kn += a * a;
        }
        knmx = fmaxf(knmx, kn);
        unsigned int w0 = bfpair(kv[0], kv[1]),  w1_ = bfpair(kv[2], kv[3]),
                     w2_ = bfpair(kv[4], kv[5]), w3_ = bfpair(kv[6], kv[7]),
                     w4_ = bfpair(kv[8], kv[9]), w5_ = bfpair(kv[10], kv[11]);
        #pragma unroll
        for (int f = 0; f < EDIM; ++f)
            kv[f] = inb[24 + f] + dot12p(inw + (24 + f) * EDIM, xr[rr]);
        unsigned int w6 = bfpair(kv[0], kv[1]),  w7 = bfpair(kv[2], kv[3]),
                     w8 = bfpair(kv[4], kv[5]),  w9 = bfpair(kv[6], kv[7]),
                     wA = bfpair(kv[8], kv[9]),  wB = bfpair(kv[10], kv[11]);
        *reinterpret_cast<uint4*>(&sKV[wv][row][0]) = make_uint4(w0, w1_, w2_, w3_);
        *reinterpret_cast<uint4*>(&sKV[wv][row][4]) = make_uint4(w4_, w5_, w6, w7);
        *reinterpret_cast<uint4*>(&sKV[wv][row][8]) = make_uint4(w8, w9, wA, wB);
    }

    // wave-local max ||k||^2 over this n's 128 rows (2 rows/lane already folded)
    float mk = knmx;
    #pragma unroll
    for (int off = 32; off > 0; off >>= 1) mk = fmaxf(mk, __shfl_xor(mk, off));
    // Cauchy-Schwarz bound in log2 domain: s*L2E - M2 <= 0
    const float M20 = sqrtf(qq[0] * mk) * L2E;
    const float M21 = sqrtf(qq[1] * mk) * L2E;

    __syncthreads();   // write->read ordering safety (waves are otherwise independent)

    // ---- single-pass attention: 3 broadcast b128 per m serve both rows ----
    f2 acc0[6], acc1[6];
    #pragma unroll
    for (int j = 0; j < 6; ++j) {
        acc0[j].x = 0.f; acc0[j].y = 0.f;
        acc1[j].x = 0.f; acc1[j].y = 0.f;
    }
    float psum0 = 0.f, psum1 = 0.f;

    #pragma unroll 2
    for (int m = 0; m < LDIM; ++m) {
        uint4 A = *reinterpret_cast<const uint4*>(&sKV[wv][m][0]);
        uint4 B = *reinterpret_cast<const uint4*>(&sKV[wv][m][4]);
        uint4 C = *reinterpret_cast<const uint4*>(&sKV[wv][m][8]);
        f2 k0 = up2(A.x), k1 = up2(A.y), k2 = up2(A.z),
           k3 = up2(A.w), k4 = up2(B.x), k5 = up2(B.y);
        f2 s0 = qL[0][0] * k0;
        s0 = pf(qL[0][1], k1, s0);
        s0 = pf(qL[0][2], k2, s0);
        s0 = pf(qL[0][3], k3, s0);
        s0 = pf(qL[0][4], k4, s0);
        s0 = pf(qL[0][5], k5, s0);
        f2 s1 = qL[1][0] * k0;
        s1 = pf(qL[1][1], k1, s1);
        s1 = pf(qL[1][2], k2, s1);
        s1 = pf(qL[1][3], k3, s1);
        s1 = pf(qL[1][4], k4, s1);
        s1 = pf(qL[1][5], k5, s1);
        float pe0 = ex2_(s0.x + s0.y - M20);
        float pe1 = ex2_(s1.x + s1.y - M21);
        psum0 += pe0;
        psum1 += pe1;
        f2 v0 = up2(B.z), v1 = up2(B.w), v2 = up2(C.x),
           v3 = up2(C.y), v4 = up2(C.z), v5 = up2(C.w);
        f2 pp0; pp0.x = pe0; pp0.y = pe0;
        f2 pp1; pp1.x = pe1; pp1.y = pe1;
        acc0[0] = pf(pp0, v0, acc0[0]); acc1[0] = pf(pp1, v0, acc1[0]);
        acc0[1] = pf(pp0, v1, acc0[1]); acc1[1] = pf(pp1, v1, acc1[1]);
        acc0[2] = pf(pp0, v2, acc0[2]); acc1[2] = pf(pp1, v2, acc1[2]);
        acc0[3] = pf(pp0, v3, acc0[3]); acc1[3] = pf(pp1, v3, acc1[3]);
        acc0[4] = pf(pp0, v4, acc0[4]); acc1[4] = pf(pp1, v4, acc1[4]);
        acc0[5] = pf(pp0, v5, acc0[5]); acc1[5] = pf(pp1, v5, acc1[5]);
    }

    // ---- per-row epilogue: out-proj + LN1 + MLP + LN2 + store ----
    #pragma unroll
    for (int rr = 0; rr < 2; ++rr) {
        const float psum = rr ? psum1 : psum0;
        const float inv = rcp_(fmaxf(psum, 1e-35f));
        f2 at[6];
        #pragma unroll
        for (int j = 0; j < 6; ++j) {
            f2 a = rr ? acc1[j] : acc0[j];
            at[j].x = a.x * inv; at[j].y = a.y * inv;
        }

        f2 r[6];
        #pragma unroll
        for (int f = 0; f < EDIM; f += 2) {
            float a0 = ob[f]     + dot12p(ow + f * EDIM,       at);
            float a1 = ob[f + 1] + dot12p(ow + (f + 1) * EDIM, at);
            f2 t; t.x = a0; t.y = a1;
            r[f >> 1] = xr[rr][f >> 1] + t;
        }
        f2 sm = r[0] + r[1] + r[2] + r[3] + r[4] + r[5];
        float mu = (sm.x + sm.y) * (1.0f / 12.0f);
        f2 mub; mub.x = mu; mub.y = mu;
        f2 vs = {0.f, 0.f};
        #pragma unroll
        for (int j = 0; j < 6; ++j) { f2 d = r[j] - mub; vs = pf(d, d, vs); }
        float rs = rsq_((vs.x + vs.y) * (1.0f / 12.0f) + 1e-5f);
        f2 rsb; rsb.x = rs; rsb.y = rs;
        const f2* g1p  = reinterpret_cast<const f2*>(g1);
        const f2* be1p = reinterpret_cast<const f2*>(be1);
        f2 y[6];
        #pragma unroll
        for (int j = 0; j < 6; ++j)
            y[j] = pf((r[j] - mub) * rsb, g1p[j], be1p[j]);

        f2 h1[16];
        #pragma unroll
        for (int h = 0; h < HDIM; h += 2) {
            float a0 = tanh_(b1[h]     + dot12p(w1 + h * EDIM,       y));
            float a1 = tanh_(b1[h + 1] + dot12p(w1 + (h + 1) * EDIM, y));
            f2 t; t.x = a0; t.y = a1;
            h1[h >> 1] = t;
        }
        f2 h2[16];
        #pragma unroll
        for (int g = 0; g < HDIM; g += 2) {
            float a0 = tanh_(b2[g]     + dot32p(w2 + g * HDIM,       h1));
            float a1 = tanh_(b2[g + 1] + dot32p(w2 + (g + 1) * HDIM, h1));
            f2 t; t.x = a0; t.y = a1;
            h2[g >> 1] = t;
        }
        f2 r2[6];
        #pragma unroll
        for (int e = 0; e < EDIM; e += 2) {
            float a0 = tanh_(b3[e]     + dot32p(w3 + e * HDIM,       h2));
            float a1 = tanh_(b3[e + 1] + dot32p(w3 + (e + 1) * HDIM, h2));
            f2 t; t.x = a0; t.y = a1;
            r2[e >> 1] = y[e >> 1] + t;
        }

        f2 sm2 = r2[0] + r2[1] + r2[2] + r2[3] + r2[4] + r2[5];
        float mu2 = (sm2.x + sm2.y) * (1.0f / 12.0f);
        f2 mub2; mub2.x = mu2; mub2.y = mu2;
        f2 vs2 = {0.f, 0.f};
        #pragma unroll
        for (int j = 0; j < 6; ++j) { f2 d = r2[j] - mub2; vs2 = pf(d, d, vs2); }
        float rs2 = rsq_((vs2.x + vs2.y) * (1.0f / 12.0f) + 1e-5f);
        f2 rsb2; rsb2.x = rs2; rsb2.y = rs2;
        const f2* g2p  = reinterpret_cast<const f2*>(g2);
        const f2* be2p = reinterpret_cast<const f2*>(be2);
        f2 z[6];
        #pragma unroll
        for (int j = 0; j < 6; ++j)
            z[j] = pf((r2[j] - mub2) * rsb2, g2p[j], be2p[j]);

        float* orow = out + ((size_t)(ln + 64 * rr) * NDIM + n) * EDIM;
        *reinterpret_cast<float4*>(orow)     = make_float4(z[0].x, z[0].y, z[1].x, z[1].y);
        *reinterpret_cast<float4*>(orow + 4) = make_float4(z[2].x, z[2].y, z[3].x, z[3].y);
        *reinterpret_cast<float4*>(orow + 8) = make_float4(z[4].x, z[4].y, z[5].x, z[5].y);
    }
}

extern "C" void kernel_launch(void* const* d_in, const int* in_sizes, int n_in,
                              void* d_out, int out_size, void* d_ws, size_t ws_size,
                              hipStream_t stream) {
    const float* x   = (const float*)d_in[0];
    const float* inw = (const float*)d_in[1];
    const float* inb = (const float*)d_in[2];
    const float* ow  = (const float*)d_in[3];
    const float* ob  = (const float*)d_in[4];
    const float* w1  = (const float*)d_in[5];
    const float* b1  = (const float*)d_in[6];
    const float* w2  = (const float*)d_in[7];
    const float* b2  = (const float*)d_in[8];
    const float* w3  = (const float*)d_in[9];
    const float* b3  = (const float*)d_in[10];
    const float* g1  = (const float*)d_in[11];
    const float* be1 = (const float*)d_in[12];
    const float* g2  = (const float*)d_in[13];
    const float* be2 = (const float*)d_in[14];
    float* out = (float*)d_out;

    encoder_fused<<<dim3(NDIM / 4), dim3(256), 0, stream>>>(
        x, inw, inb, ow, ob, w1, b1, w2, b2, w3, b3, g1, be1, g2, be2, out);
}